// Round 1
// baseline (1743.274 us; speedup 1.0000x reference)
//
#include <hip/hip_runtime.h>
#include <hip/hip_fp16.h>

#define T_TOK 16384
#define C_DIM 1024
#define F_DIM 4096
#define E_NUM 8

typedef _Float16 half8 __attribute__((ext_vector_type(8)));
typedef float f32x4 __attribute__((ext_vector_type(4)));

// ---- workspace layout (bytes) ----
static constexpr size_t META_OFF  = 0;                                        // 26 ints: counts[8], rowOff[9], tileOff[9]
static constexpr size_t XB_OFF    = 256;                                      // x fp16 [T][C]
static constexpr size_t W1T_OFF   = XB_OFF  + (size_t)2*T_TOK*C_DIM;          // w1^T fp16 [E][F][C]
static constexpr size_t W2T_OFF   = W1T_OFF + (size_t)2*E_NUM*C_DIM*F_DIM;    // w2^T fp16 [E][C][F]
static constexpr size_t HB_OFF    = W2T_OFF + (size_t)2*E_NUM*C_DIM*F_DIM;    // h fp16 [T*K][F]
static constexpr size_t YB_OFF    = HB_OFF  + (size_t)2*T_TOK*2*F_DIM;        // y fp16 [T*K][C]
static constexpr size_t TOK_OFF   = YB_OFF  + (size_t)2*T_TOK*2*C_DIM;        // int [E][T]
static constexpr size_t GATE_OFF  = TOK_OFF + (size_t)4*E_NUM*T_TOK;          // float [E][T]
static constexpr size_t TSLOT_OFF = GATE_OFF+ (size_t)4*E_NUM*T_TOK;          // int [T][2]  (e<<24)|idx
static constexpr size_t WS_NEED   = TSLOT_OFF + (size_t)4*T_TOK*2;

__device__ __forceinline__ void async16(void* lds, const void* g) {
  // dest = wave-uniform base + lane*16 (hardware rule); source is per-lane.
  __builtin_amdgcn_global_load_lds((const __attribute__((address_space(1))) unsigned int*)g,
                                   (__attribute__((address_space(3))) unsigned int*)lds,
                                   16, 0, 0);
}

// ---- cast x fp32 -> fp16 ----
__global__ __launch_bounds__(256) void cast_x_kernel(const float* __restrict__ x,
                                                     _Float16* __restrict__ xb) {
  size_t i = ((size_t)blockIdx.x * 256 + threadIdx.x) * 8;
  float4 a = *(const float4*)(x + i);
  float4 b = *(const float4*)(x + i + 4);
  half8 h;
  h[0]=(_Float16)a.x; h[1]=(_Float16)a.y; h[2]=(_Float16)a.z; h[3]=(_Float16)a.w;
  h[4]=(_Float16)b.x; h[5]=(_Float16)b.y; h[6]=(_Float16)b.z; h[7]=(_Float16)b.w;
  *(half8*)(xb + i) = h;
}

// ---- transpose + cast: in fp32 [R][Cc] per expert -> out fp16 [Cc][R] ----
__global__ __launch_bounds__(256) void transpose_cast_kernel(const float* __restrict__ in,
                                                             _Float16* __restrict__ outp,
                                                             int R, int Cc) {
  __shared__ float tile[32][33];
  int e = blockIdx.z;
  const float* ip = in + (size_t)e * R * Cc;
  _Float16* op = outp + (size_t)e * R * Cc;
  int c0 = blockIdx.x * 32, r0 = blockIdx.y * 32;
  int tx = threadIdx.x & 31, ty = threadIdx.x >> 5;
  #pragma unroll
  for (int d = 0; d < 32; d += 8)
    tile[ty + d][tx] = ip[(size_t)(r0 + ty + d) * Cc + c0 + tx];
  __syncthreads();
  #pragma unroll
  for (int d = 0; d < 32; d += 8)
    op[(size_t)(c0 + ty + d) * R + r0 + tx] = (_Float16)tile[tx][ty + d];
}

// ---- router: fp64 logits, softmax, top-2 (tie -> lower index), gates ----
__global__ __launch_bounds__(256) void router_kernel(const float* __restrict__ x,
                                                     const float* __restrict__ rw,
                                                     int* __restrict__ counts,
                                                     int* __restrict__ tok,
                                                     float* __restrict__ gate,
                                                     int* __restrict__ tslot) {
  int wv = threadIdx.x >> 6, l = threadIdx.x & 63;
  int t = blockIdx.x * 4 + wv;
  const float* xr = x + (size_t)t * C_DIM;
  double acc[E_NUM] = {};
  #pragma unroll
  for (int j = 0; j < 4; ++j) {
    float4 xv = *(const float4*)(xr + j * 256 + l * 4);
    #pragma unroll
    for (int e = 0; e < E_NUM; ++e) {
      float4 w4 = *(const float4*)(rw + (size_t)e * C_DIM + j * 256 + l * 4);
      acc[e] += (double)xv.x * w4.x + (double)xv.y * w4.y +
                (double)xv.z * w4.z + (double)xv.w * w4.w;
    }
  }
  #pragma unroll
  for (int e = 0; e < E_NUM; ++e)
    #pragma unroll
    for (int off = 32; off; off >>= 1)
      acc[e] += __shfl_xor(acc[e], off, 64);

  if (l == 0) {
    double m = acc[0];
    #pragma unroll
    for (int e = 1; e < E_NUM; ++e) m = acc[e] > m ? acc[e] : m;
    double p[E_NUM], s = 0.0;
    #pragma unroll
    for (int e = 0; e < E_NUM; ++e) { p[e] = exp(acc[e] - m); s += p[e]; }
    int i0 = 0; double b0 = p[0];
    #pragma unroll
    for (int e = 1; e < E_NUM; ++e) if (p[e] > b0) { b0 = p[e]; i0 = e; }
    int i1 = -1; double b1v = -1.0;
    #pragma unroll
    for (int e = 0; e < E_NUM; ++e) if (e != i0 && p[e] > b1v) { b1v = p[e]; i1 = e; }
    double q0 = b0 / s, q1 = b1v / s;
    double den = q0 + q1 + 1e-9;
    float g0 = (float)(q0 / den), g1 = (float)(q1 / den);
    int idx0 = atomicAdd(&counts[i0], 1);
    tok[i0 * T_TOK + idx0] = t; gate[i0 * T_TOK + idx0] = g0;
    tslot[t * 2] = (i0 << 24) | idx0;
    int idx1 = atomicAdd(&counts[i1], 1);
    tok[i1 * T_TOK + idx1] = t; gate[i1 * T_TOK + idx1] = g1;
    tslot[t * 2 + 1] = (i1 << 24) | idx1;
  }
}

// ---- prefix sums: rowOff (meta[8..16]) and tileOff (meta[17..25]) ----
__global__ void plan_kernel(int* meta) {
  if (threadIdx.x == 0 && blockIdx.x == 0) {
    int ro = 0, to = 0;
    meta[8] = 0; meta[17] = 0;
    for (int e = 0; e < E_NUM; ++e) {
      int c = meta[e];
      ro += c; to += (c + 127) >> 7;
      meta[9 + e] = ro; meta[18 + e] = to;
    }
  }
}

// ---- grouped GEMM1: h = gelu(x[tok] @ w1[e] + b1[e]) ----
__global__ __launch_bounds__(256) void gemm1_kernel(const _Float16* __restrict__ xb,
                                                    const _Float16* __restrict__ w1t,
                                                    const float* __restrict__ b1,
                                                    _Float16* __restrict__ hbuf,
                                                    const int* __restrict__ tok,
                                                    const int* __restrict__ meta) {
  __shared__ _Float16 As[128 * 64];
  __shared__ _Float16 Bs[128 * 64];
  __shared__ int tokLds[128];
  int bx = blockIdx.x;
  if (bx >= meta[17 + E_NUM]) return;
  int e = 0;
  while (bx >= meta[18 + e]) ++e;
  int ne = meta[e];
  int r0 = (bx - meta[17 + e]) << 7;
  int valid = ne - r0; if (valid > 128) valid = 128;
  int tid = threadIdx.x;
  if (tid < 128) {
    int r = tid < valid ? tid : valid - 1;
    tokLds[tid] = tok[e * T_TOK + r0 + r];
  }
  __syncthreads();
  int w = tid >> 6, l = tid & 63;
  int by = blockIdx.y;
  const _Float16* aSrc[4];
  const _Float16* bSrc[4];
  #pragma unroll
  for (int i = 0; i < 4; ++i) {
    int c = i * 256 + tid, row = c >> 3, k8 = c & 7;
    aSrc[i] = xb + (size_t)tokLds[row] * C_DIM + k8 * 8;
    bSrc[i] = w1t + ((size_t)e * F_DIM + by * 128 + row) * C_DIM + k8 * 8;
  }
  f32x4 acc[4][4] = {};
  int wm = w >> 1, wn = w & 1;
  for (int kt = 0; kt < C_DIM / 64; ++kt) {
    __syncthreads();
    #pragma unroll
    for (int i = 0; i < 4; ++i) {
      async16(&As[(i * 256 + w * 64) * 8], aSrc[i] + kt * 64);
      async16(&Bs[(i * 256 + w * 64) * 8], bSrc[i] + kt * 64);
    }
    __syncthreads();
    #pragma unroll
    for (int ks = 0; ks < 2; ++ks) {
      half8 af[4], bf[4];
      #pragma unroll
      for (int m = 0; m < 4; ++m)
        af[m] = *(const half8*)&As[(wm * 64 + m * 16 + (l & 15)) * 64 + ks * 32 + (l >> 4) * 8];
      #pragma unroll
      for (int n = 0; n < 4; ++n)
        bf[n] = *(const half8*)&Bs[(wn * 64 + n * 16 + (l & 15)) * 64 + ks * 32 + (l >> 4) * 8];
      #pragma unroll
      for (int m = 0; m < 4; ++m)
        #pragma unroll
        for (int n = 0; n < 4; ++n)
          acc[m][n] = __builtin_amdgcn_mfma_f32_16x16x32_f16(af[m], bf[n], acc[m][n], 0, 0, 0);
    }
  }
  int hbase = meta[8 + e] + r0;
  float bv[4];
  #pragma unroll
  for (int n = 0; n < 4; ++n)
    bv[n] = b1[(size_t)e * F_DIM + by * 128 + wn * 64 + n * 16 + (l & 15)];
  #pragma unroll
  for (int m = 0; m < 4; ++m) {
    int rb = wm * 64 + m * 16 + (l >> 4) * 4;
    #pragma unroll
    for (int n = 0; n < 4; ++n) {
      int col = by * 128 + wn * 64 + n * 16 + (l & 15);
      #pragma unroll
      for (int r = 0; r < 4; ++r) {
        int row = rb + r;
        if (row < valid) {
          float pre = acc[m][n][r] + bv[n];
          float g = 0.5f * pre * (1.0f + erff(pre * 0.70710678118654752f));
          hbuf[(size_t)(hbase + row) * F_DIM + col] = (_Float16)g;
        }
      }
    }
  }
}

// ---- grouped GEMM2: ybuf = gate * (h @ w2[e] + b2[e]) ----
__global__ __launch_bounds__(256) void gemm2_kernel(const _Float16* __restrict__ hbuf,
                                                    const _Float16* __restrict__ w2t,
                                                    const float* __restrict__ b2,
                                                    _Float16* __restrict__ ybuf,
                                                    const float* __restrict__ gate,
                                                    const int* __restrict__ meta) {
  __shared__ _Float16 As[128 * 64];
  __shared__ _Float16 Bs[128 * 64];
  __shared__ float gateLds[128];
  int bx = blockIdx.x;
  if (bx >= meta[17 + E_NUM]) return;
  int e = 0;
  while (bx >= meta[18 + e]) ++e;
  int ne = meta[e];
  int r0 = (bx - meta[17 + e]) << 7;
  int valid = ne - r0; if (valid > 128) valid = 128;
  int tid = threadIdx.x;
  int hbase = meta[8 + e] + r0;
  if (tid < 128) {
    int r = tid < valid ? tid : valid - 1;
    gateLds[tid] = gate[e * T_TOK + r0 + r];
  }
  __syncthreads();
  int w = tid >> 6, l = tid & 63;
  int by = blockIdx.y;
  const _Float16* aSrc[4];
  const _Float16* bSrc[4];
  #pragma unroll
  for (int i = 0; i < 4; ++i) {
    int c = i * 256 + tid, row = c >> 3, k8 = c & 7;
    int rowc = row < valid ? row : valid - 1;
    aSrc[i] = hbuf + (size_t)(hbase + rowc) * F_DIM + k8 * 8;
    bSrc[i] = w2t + ((size_t)e * C_DIM + by * 128 + row) * F_DIM + k8 * 8;
  }
  f32x4 acc[4][4] = {};
  int wm = w >> 1, wn = w & 1;
  for (int kt = 0; kt < F_DIM / 64; ++kt) {
    __syncthreads();
    #pragma unroll
    for (int i = 0; i < 4; ++i) {
      async16(&As[(i * 256 + w * 64) * 8], aSrc[i] + kt * 64);
      async16(&Bs[(i * 256 + w * 64) * 8], bSrc[i] + kt * 64);
    }
    __syncthreads();
    #pragma unroll
    for (int ks = 0; ks < 2; ++ks) {
      half8 af[4], bf[4];
      #pragma unroll
      for (int m = 0; m < 4; ++m)
        af[m] = *(const half8*)&As[(wm * 64 + m * 16 + (l & 15)) * 64 + ks * 32 + (l >> 4) * 8];
      #pragma unroll
      for (int n = 0; n < 4; ++n)
        bf[n] = *(const half8*)&Bs[(wn * 64 + n * 16 + (l & 15)) * 64 + ks * 32 + (l >> 4) * 8];
      #pragma unroll
      for (int m = 0; m < 4; ++m)
        #pragma unroll
        for (int n = 0; n < 4; ++n)
          acc[m][n] = __builtin_amdgcn_mfma_f32_16x16x32_f16(af[m], bf[n], acc[m][n], 0, 0, 0);
    }
  }
  float bv[4];
  #pragma unroll
  for (int n = 0; n < 4; ++n)
    bv[n] = b2[(size_t)e * C_DIM + by * 128 + wn * 64 + n * 16 + (l & 15)];
  #pragma unroll
  for (int m = 0; m < 4; ++m) {
    int rb = wm * 64 + m * 16 + (l >> 4) * 4;
    #pragma unroll
    for (int n = 0; n < 4; ++n) {
      int col = by * 128 + wn * 64 + n * 16 + (l & 15);
      #pragma unroll
      for (int r = 0; r < 4; ++r) {
        int row = rb + r;
        if (row < valid) {
          float val = gateLds[row] * (acc[m][n][r] + bv[n]);
          ybuf[(size_t)(hbase + row) * C_DIM + col] = (_Float16)val;
        }
      }
    }
  }
}

// ---- combine: out[t] = y(slot0) + y(slot1) ----
__global__ __launch_bounds__(256) void combine_kernel(const _Float16* __restrict__ ybuf,
                                                      const int* __restrict__ tslot,
                                                      const int* __restrict__ meta,
                                                      float* __restrict__ out) {
  int gid = blockIdx.x * 256 + threadIdx.x;
  int t = gid >> 7;
  int cc = (gid & 127) << 3;
  int s0 = tslot[t * 2], s1 = tslot[t * 2 + 1];
  size_t r0 = (size_t)meta[8 + (s0 >> 24)] + (s0 & 0xFFFFFF);
  size_t r1 = (size_t)meta[8 + (s1 >> 24)] + (s1 & 0xFFFFFF);
  half8 y0 = *(const half8*)(ybuf + r0 * C_DIM + cc);
  half8 y1 = *(const half8*)(ybuf + r1 * C_DIM + cc);
  float4 o0, o1;
  o0.x = (float)y0[0] + (float)y1[0];
  o0.y = (float)y0[1] + (float)y1[1];
  o0.z = (float)y0[2] + (float)y1[2];
  o0.w = (float)y0[3] + (float)y1[3];
  o1.x = (float)y0[4] + (float)y1[4];
  o1.y = (float)y0[5] + (float)y1[5];
  o1.z = (float)y0[6] + (float)y1[6];
  o1.w = (float)y0[7] + (float)y1[7];
  *(float4*)(out + (size_t)t * C_DIM + cc) = o0;
  *(float4*)(out + (size_t)t * C_DIM + cc + 4) = o1;
}

extern "C" void kernel_launch(void* const* d_in, const int* in_sizes, int n_in,
                              void* d_out, int out_size, void* d_ws, size_t ws_size,
                              hipStream_t stream) {
  (void)in_sizes; (void)n_in; (void)out_size;
  if (!d_ws || ws_size < WS_NEED) return;  // need ~481 MiB scratch

  const float* x  = (const float*)d_in[0];
  const float* rw = (const float*)d_in[1];
  const float* w1 = (const float*)d_in[2];
  const float* b1 = (const float*)d_in[3];
  const float* w2 = (const float*)d_in[4];
  const float* b2 = (const float*)d_in[5];
  float* out = (float*)d_out;

  char* ws = (char*)d_ws;
  int*       meta  = (int*)(ws + META_OFF);
  _Float16*  xb    = (_Float16*)(ws + XB_OFF);
  _Float16*  w1t   = (_Float16*)(ws + W1T_OFF);
  _Float16*  w2t   = (_Float16*)(ws + W2T_OFF);
  _Float16*  hbuf  = (_Float16*)(ws + HB_OFF);
  _Float16*  ybuf  = (_Float16*)(ws + YB_OFF);
  int*       tok   = (int*)(ws + TOK_OFF);
  float*     gate  = (float*)(ws + GATE_OFF);
  int*       tslot = (int*)(ws + TSLOT_OFF);

  hipMemsetAsync(meta, 0, 256, stream);

  cast_x_kernel<<<(T_TOK * C_DIM / 8) / 256, 256, 0, stream>>>(x, xb);
  transpose_cast_kernel<<<dim3(F_DIM / 32, C_DIM / 32, E_NUM), 256, 0, stream>>>(w1, w1t, C_DIM, F_DIM);
  transpose_cast_kernel<<<dim3(C_DIM / 32, F_DIM / 32, E_NUM), 256, 0, stream>>>(w2, w2t, F_DIM, C_DIM);
  router_kernel<<<T_TOK / 4, 256, 0, stream>>>(x, rw, meta, tok, gate, tslot);
  plan_kernel<<<1, 64, 0, stream>>>(meta);

  // max tiles = T*K/128 + E = 264
  gemm1_kernel<<<dim3(264, F_DIM / 128), 256, 0, stream>>>(xb, w1t, b1, hbuf, tok, meta);
  gemm2_kernel<<<dim3(264, C_DIM / 128), 256, 0, stream>>>(hbuf, w2t, b2, ybuf, gate, meta);
  combine_kernel<<<(T_TOK * (C_DIM / 8)) / 256, 256, 0, stream>>>(ybuf, tslot, meta, out);
}

// Round 2
// 1627.527 us; speedup vs baseline: 1.0711x; 1.0711x over previous
//
#include <hip/hip_runtime.h>
#include <hip/hip_fp16.h>

#define T_TOK 16384
#define C_DIM 1024
#define F_DIM 4096
#define E_NUM 8

typedef _Float16 half8 __attribute__((ext_vector_type(8)));
typedef float f32x4 __attribute__((ext_vector_type(4)));

// ---- workspace layout (bytes) ----
static constexpr size_t META_OFF  = 0;                                        // ints: counts[8], rowOff[9], tileOff[9]
static constexpr size_t XB_OFF    = 256;                                      // x fp16 [T][C]
static constexpr size_t W1T_OFF   = XB_OFF  + (size_t)2*T_TOK*C_DIM;          // w1^T fp16 [E][F][C]
static constexpr size_t W2T_OFF   = W1T_OFF + (size_t)2*E_NUM*C_DIM*F_DIM;    // w2^T fp16 [E][C][F]
static constexpr size_t HB_OFF    = W2T_OFF + (size_t)2*E_NUM*C_DIM*F_DIM;    // h fp16 [T*K][F]
static constexpr size_t YB_OFF    = HB_OFF  + (size_t)2*T_TOK*2*F_DIM;        // y fp16 [T*K][C]
static constexpr size_t TOK_OFF   = YB_OFF  + (size_t)2*T_TOK*2*C_DIM;        // int [E][T]
static constexpr size_t GATE_OFF  = TOK_OFF + (size_t)4*E_NUM*T_TOK;          // float [E][T]
static constexpr size_t TSLOT_OFF = GATE_OFF+ (size_t)4*E_NUM*T_TOK;          // int [T][2]  (e<<24)|idx
static constexpr size_t WS_NEED   = TSLOT_OFF + (size_t)4*T_TOK*2;

__device__ __forceinline__ void async16(void* lds, const void* g) {
  // dest = wave-uniform base + lane*16 (hardware rule); source IS per-lane.
  __builtin_amdgcn_global_load_lds((const __attribute__((address_space(1))) unsigned int*)g,
                                   (__attribute__((address_space(3))) unsigned int*)lds,
                                   16, 0, 0);
}

// ---- cast x fp32 -> fp16 ----
__global__ __launch_bounds__(256) void cast_x_kernel(const float* __restrict__ x,
                                                     _Float16* __restrict__ xb) {
  size_t i = ((size_t)blockIdx.x * 256 + threadIdx.x) * 8;
  float4 a = *(const float4*)(x + i);
  float4 b = *(const float4*)(x + i + 4);
  half8 h;
  h[0]=(_Float16)a.x; h[1]=(_Float16)a.y; h[2]=(_Float16)a.z; h[3]=(_Float16)a.w;
  h[4]=(_Float16)b.x; h[5]=(_Float16)b.y; h[6]=(_Float16)b.z; h[7]=(_Float16)b.w;
  *(half8*)(xb + i) = h;
}

// ---- transpose + cast: in fp32 [R][Cc] per expert -> out fp16 [Cc][R] ----
__global__ __launch_bounds__(256) void transpose_cast_kernel(const float* __restrict__ in,
                                                             _Float16* __restrict__ outp,
                                                             int R, int Cc) {
  __shared__ float tile[32][33];
  int e = blockIdx.z;
  const float* ip = in + (size_t)e * R * Cc;
  _Float16* op = outp + (size_t)e * R * Cc;
  int c0 = blockIdx.x * 32, r0 = blockIdx.y * 32;
  int tx = threadIdx.x & 31, ty = threadIdx.x >> 5;
  #pragma unroll
  for (int d = 0; d < 32; d += 8)
    tile[ty + d][tx] = ip[(size_t)(r0 + ty + d) * Cc + c0 + tx];
  __syncthreads();
  #pragma unroll
  for (int d = 0; d < 32; d += 8)
    op[(size_t)(c0 + ty + d) * R + r0 + tx] = (_Float16)tile[tx][ty + d];
}

// ---- router: fp64 logits, softmax, top-2 (tie -> lower index), gates ----
__global__ __launch_bounds__(256) void router_kernel(const float* __restrict__ x,
                                                     const float* __restrict__ rw,
                                                     int* __restrict__ counts,
                                                     int* __restrict__ tok,
                                                     float* __restrict__ gate,
                                                     int* __restrict__ tslot) {
  int wv = threadIdx.x >> 6, l = threadIdx.x & 63;
  int t = blockIdx.x * 4 + wv;
  const float* xr = x + (size_t)t * C_DIM;
  double acc[E_NUM] = {};
  #pragma unroll
  for (int j = 0; j < 4; ++j) {
    float4 xv = *(const float4*)(xr + j * 256 + l * 4);
    #pragma unroll
    for (int e = 0; e < E_NUM; ++e) {
      float4 w4 = *(const float4*)(rw + (size_t)e * C_DIM + j * 256 + l * 4);
      acc[e] += (double)xv.x * w4.x + (double)xv.y * w4.y +
                (double)xv.z * w4.z + (double)xv.w * w4.w;
    }
  }
  #pragma unroll
  for (int e = 0; e < E_NUM; ++e)
    #pragma unroll
    for (int off = 32; off; off >>= 1)
      acc[e] += __shfl_xor(acc[e], off, 64);

  if (l == 0) {
    double m = acc[0];
    #pragma unroll
    for (int e = 1; e < E_NUM; ++e) m = acc[e] > m ? acc[e] : m;
    double p[E_NUM], s = 0.0;
    #pragma unroll
    for (int e = 0; e < E_NUM; ++e) { p[e] = exp(acc[e] - m); s += p[e]; }
    int i0 = 0; double b0 = p[0];
    #pragma unroll
    for (int e = 1; e < E_NUM; ++e) if (p[e] > b0) { b0 = p[e]; i0 = e; }
    int i1 = -1; double b1v = -1.0;
    #pragma unroll
    for (int e = 0; e < E_NUM; ++e) if (e != i0 && p[e] > b1v) { b1v = p[e]; i1 = e; }
    double q0 = b0 / s, q1 = b1v / s;
    double den = q0 + q1 + 1e-9;
    float g0 = (float)(q0 / den), g1 = (float)(q1 / den);
    int idx0 = atomicAdd(&counts[i0], 1);
    tok[i0 * T_TOK + idx0] = t; gate[i0 * T_TOK + idx0] = g0;
    tslot[t * 2] = (i0 << 24) | idx0;
    int idx1 = atomicAdd(&counts[i1], 1);
    tok[i1 * T_TOK + idx1] = t; gate[i1 * T_TOK + idx1] = g1;
    tslot[t * 2 + 1] = (i1 << 24) | idx1;
  }
}

// ---- prefix sums: rowOff (meta[8..16]) and 256-row tileOff (meta[17..25]) ----
__global__ void plan_kernel(int* meta) {
  if (threadIdx.x == 0 && blockIdx.x == 0) {
    int ro = 0, to = 0;
    meta[8] = 0; meta[17] = 0;
    for (int e = 0; e < E_NUM; ++e) {
      int c = meta[e];
      ro += c; to += (c + 255) >> 8;
      meta[9 + e] = ro; meta[18 + e] = to;
    }
  }
}

// ============================================================================
// 256x256 grouped GEMM, BK=64, 8 waves (2Mx4N), double-buffered LDS (128 KiB),
// counted vmcnt(8) + raw s_barrier (T3/T4), XOR chunk swizzle (T2, both-sides
// via pre-swizzled global_load_lds source), setprio around MFMA (T5).
// LDS tile: [256 rows][8 chunks of 16B]; LDS[row][j] = G[row][j ^ (row&7)].
// Reader: chunk c = ks*4 + (l>>4) at byte row*128 + ((c ^ (l&7))*16).
// ============================================================================

// ---- grouped GEMM1: h = gelu(x[tok] @ w1[e] + b1[e]) ----
__global__ __launch_bounds__(512, 2) void gemm1_kernel(const _Float16* __restrict__ xb,
                                                       const _Float16* __restrict__ w1t,
                                                       const float* __restrict__ b1,
                                                       _Float16* __restrict__ hbuf,
                                                       const int* __restrict__ tok,
                                                       const int* __restrict__ meta) {
  __shared__ _Float16 smem[65536];   // 2 bufs x (A 256x64 + B 256x64) fp16
  __shared__ int tokLds[256];

  // bijective XCD swizzle (nwg=2176, q=272, r=0), then M-supertile ordering
  int bid = blockIdx.x;
  int swz = (bid & 7) * 272 + (bid >> 3);
  int mt = swz >> 4, nt = swz & 15;          // 16 N-tiles (F/256)
  if (mt >= meta[17 + E_NUM]) return;
  int e = 0;
  while (mt >= meta[18 + e]) ++e;
  int ne = meta[e];
  int r0 = (mt - meta[17 + e]) << 8;
  int valid = ne - r0; if (valid > 256) valid = 256;

  int tid = threadIdx.x;
  if (tid < 256) {
    int r = tid < valid ? tid : valid - 1;
    tokLds[tid] = tok[e * T_TOK + r0 + r];
  }
  __syncthreads();

  // per-thread staging sources (4 A-loads + 4 B-loads per K-tile)
  const _Float16* aP[4];
  const _Float16* bP[4];
  #pragma unroll
  for (int i = 0; i < 4; ++i) {
    int s = i * 512 + tid, row = s >> 3;
    int ch = (s & 7) ^ (row & 7);
    aP[i] = xb + (size_t)tokLds[row] * C_DIM + ch * 8;
    bP[i] = w1t + ((size_t)e * F_DIM + nt * 256 + row) * C_DIM + ch * 8;
  }

  constexpr int NT = C_DIM / 64;   // 16
  // prologue: stage kt0 -> buf0, kt1 -> buf1  (8 loads each)
  #pragma unroll
  for (int i = 0; i < 4; ++i) {
    int s = i * 512 + tid;
    async16(smem + s * 8, aP[i]);
    async16(smem + 16384 + s * 8, bP[i]);
  }
  #pragma unroll
  for (int i = 0; i < 4; ++i) {
    int s = i * 512 + tid;
    async16(smem + 32768 + s * 8, aP[i] + 64);
    async16(smem + 32768 + 16384 + s * 8, bP[i] + 64);
  }

  int w = tid >> 6, l = tid & 63;
  int wm = w >> 2, wn = w & 3;
  int q = l >> 4;
  int aRowByte = (wm * 128 + (l & 15)) * 128;
  int bRowByte = (wn * 64 + (l & 15)) * 128;

  f32x4 acc[8][4] = {};
  int cur = 0;
  for (int t = 0; t < NT; ++t) {
    asm volatile("s_waitcnt vmcnt(8)" ::: "memory");
    __builtin_amdgcn_s_barrier();
    const char* Ab = (const char*)(smem + cur * 32768);
    const char* Bb = (const char*)(smem + cur * 32768 + 16384);
    #pragma unroll
    for (int ks = 0; ks < 2; ++ks) {
      half8 af[8], bf[4];
      int sw = ((ks * 4 + q) ^ (l & 7)) * 16;
      #pragma unroll
      for (int m = 0; m < 8; ++m)
        af[m] = *(const half8*)(Ab + aRowByte + m * 2048 + sw);
      #pragma unroll
      for (int n = 0; n < 4; ++n)
        bf[n] = *(const half8*)(Bb + bRowByte + n * 2048 + sw);
      __builtin_amdgcn_s_setprio(1);
      #pragma unroll
      for (int m = 0; m < 8; ++m)
        #pragma unroll
        for (int n = 0; n < 4; ++n)
          acc[m][n] = __builtin_amdgcn_mfma_f32_16x16x32_f16(af[m], bf[n], acc[m][n], 0, 0, 0);
      __builtin_amdgcn_s_setprio(0);
    }
    __builtin_amdgcn_s_barrier();
    int kt2 = t + 2 < NT ? t + 2 : NT - 1;
    #pragma unroll
    for (int i = 0; i < 4; ++i) {
      int s = i * 512 + tid;
      async16(smem + cur * 32768 + s * 8, aP[i] + kt2 * 64);
      async16(smem + cur * 32768 + 16384 + s * 8, bP[i] + kt2 * 64);
    }
    cur ^= 1;
  }

  // epilogue
  int hbase = meta[8 + e] + r0;
  float bv[4];
  #pragma unroll
  for (int n = 0; n < 4; ++n)
    bv[n] = b1[(size_t)e * F_DIM + nt * 256 + wn * 64 + n * 16 + (l & 15)];
  #pragma unroll
  for (int m = 0; m < 8; ++m) {
    int rb = wm * 128 + m * 16 + (l >> 4) * 4;
    #pragma unroll
    for (int n = 0; n < 4; ++n) {
      int col = nt * 256 + wn * 64 + n * 16 + (l & 15);
      #pragma unroll
      for (int r = 0; r < 4; ++r) {
        int row = rb + r;
        if (row < valid) {
          float pre = acc[m][n][r] + bv[n];
          float g = 0.5f * pre * (1.0f + erff(pre * 0.70710678118654752f));
          hbuf[(size_t)(hbase + row) * F_DIM + col] = (_Float16)g;
        }
      }
    }
  }
}

// ---- grouped GEMM2: ybuf = gate * (h @ w2[e] + b2[e]) ----
__global__ __launch_bounds__(512, 2) void gemm2_kernel(const _Float16* __restrict__ hbuf,
                                                       const _Float16* __restrict__ w2t,
                                                       const float* __restrict__ b2,
                                                       _Float16* __restrict__ ybuf,
                                                       const float* __restrict__ gate,
                                                       const int* __restrict__ meta) {
  __shared__ _Float16 smem[65536];
  __shared__ float gateLds[256];

  // bijective XCD swizzle (nwg=544, q=68, r=0)
  int bid = blockIdx.x;
  int swz = (bid & 7) * 68 + (bid >> 3);
  int mt = swz >> 2, nt = swz & 3;           // 4 N-tiles (C/256)
  if (mt >= meta[17 + E_NUM]) return;
  int e = 0;
  while (mt >= meta[18 + e]) ++e;
  int ne = meta[e];
  int r0 = (mt - meta[17 + e]) << 8;
  int valid = ne - r0; if (valid > 256) valid = 256;
  int hbase = meta[8 + e] + r0;

  int tid = threadIdx.x;
  if (tid < 256) {
    int r = tid < valid ? tid : valid - 1;
    gateLds[tid] = gate[e * T_TOK + r0 + r];
  }
  __syncthreads();

  const _Float16* aP[4];
  const _Float16* bP[4];
  #pragma unroll
  for (int i = 0; i < 4; ++i) {
    int s = i * 512 + tid, row = s >> 3;
    int ch = (s & 7) ^ (row & 7);
    int rowc = row < valid ? row : valid - 1;
    aP[i] = hbuf + (size_t)(hbase + rowc) * F_DIM + ch * 8;
    bP[i] = w2t + ((size_t)e * C_DIM + nt * 256 + row) * F_DIM + ch * 8;
  }

  constexpr int NT = F_DIM / 64;   // 64
  #pragma unroll
  for (int i = 0; i < 4; ++i) {
    int s = i * 512 + tid;
    async16(smem + s * 8, aP[i]);
    async16(smem + 16384 + s * 8, bP[i]);
  }
  #pragma unroll
  for (int i = 0; i < 4; ++i) {
    int s = i * 512 + tid;
    async16(smem + 32768 + s * 8, aP[i] + 64);
    async16(smem + 32768 + 16384 + s * 8, bP[i] + 64);
  }

  int w = tid >> 6, l = tid & 63;
  int wm = w >> 2, wn = w & 3;
  int q = l >> 4;
  int aRowByte = (wm * 128 + (l & 15)) * 128;
  int bRowByte = (wn * 64 + (l & 15)) * 128;

  f32x4 acc[8][4] = {};
  int cur = 0;
  for (int t = 0; t < NT; ++t) {
    asm volatile("s_waitcnt vmcnt(8)" ::: "memory");
    __builtin_amdgcn_s_barrier();
    const char* Ab = (const char*)(smem + cur * 32768);
    const char* Bb = (const char*)(smem + cur * 32768 + 16384);
    #pragma unroll
    for (int ks = 0; ks < 2; ++ks) {
      half8 af[8], bf[4];
      int sw = ((ks * 4 + q) ^ (l & 7)) * 16;
      #pragma unroll
      for (int m = 0; m < 8; ++m)
        af[m] = *(const half8*)(Ab + aRowByte + m * 2048 + sw);
      #pragma unroll
      for (int n = 0; n < 4; ++n)
        bf[n] = *(const half8*)(Bb + bRowByte + n * 2048 + sw);
      __builtin_amdgcn_s_setprio(1);
      #pragma unroll
      for (int m = 0; m < 8; ++m)
        #pragma unroll
        for (int n = 0; n < 4; ++n)
          acc[m][n] = __builtin_amdgcn_mfma_f32_16x16x32_f16(af[m], bf[n], acc[m][n], 0, 0, 0);
      __builtin_amdgcn_s_setprio(0);
    }
    __builtin_amdgcn_s_barrier();
    int kt2 = t + 2 < NT ? t + 2 : NT - 1;
    #pragma unroll
    for (int i = 0; i < 4; ++i) {
      int s = i * 512 + tid;
      async16(smem + cur * 32768 + s * 8, aP[i] + kt2 * 64);
      async16(smem + cur * 32768 + 16384 + s * 8, bP[i] + kt2 * 64);
    }
    cur ^= 1;
  }

  float bv[4];
  #pragma unroll
  for (int n = 0; n < 4; ++n)
    bv[n] = b2[(size_t)e * C_DIM + nt * 256 + wn * 64 + n * 16 + (l & 15)];
  #pragma unroll
  for (int m = 0; m < 8; ++m) {
    int rb = wm * 128 + m * 16 + (l >> 4) * 4;
    #pragma unroll
    for (int n = 0; n < 4; ++n) {
      int col = nt * 256 + wn * 64 + n * 16 + (l & 15);
      #pragma unroll
      for (int r = 0; r < 4; ++r) {
        int row = rb + r;
        if (row < valid) {
          float val = gateLds[row] * (acc[m][n][r] + bv[n]);
          ybuf[(size_t)(hbase + row) * C_DIM + col] = (_Float16)val;
        }
      }
    }
  }
}

// ---- combine: out[t] = y(slot0) + y(slot1) ----
__global__ __launch_bounds__(256) void combine_kernel(const _Float16* __restrict__ ybuf,
                                                      const int* __restrict__ tslot,
                                                      const int* __restrict__ meta,
                                                      float* __restrict__ out) {
  int gid = blockIdx.x * 256 + threadIdx.x;
  int t = gid >> 7;
  int cc = (gid & 127) << 3;
  int s0 = tslot[t * 2], s1 = tslot[t * 2 + 1];
  size_t r0 = (size_t)meta[8 + (s0 >> 24)] + (s0 & 0xFFFFFF);
  size_t r1 = (size_t)meta[8 + (s1 >> 24)] + (s1 & 0xFFFFFF);
  half8 y0 = *(const half8*)(ybuf + r0 * C_DIM + cc);
  half8 y1 = *(const half8*)(ybuf + r1 * C_DIM + cc);
  float4 o0, o1;
  o0.x = (float)y0[0] + (float)y1[0];
  o0.y = (float)y0[1] + (float)y1[1];
  o0.z = (float)y0[2] + (float)y1[2];
  o0.w = (float)y0[3] + (float)y1[3];
  o1.x = (float)y0[4] + (float)y1[4];
  o1.y = (float)y0[5] + (float)y1[5];
  o1.z = (float)y0[6] + (float)y1[6];
  o1.w = (float)y0[7] + (float)y1[7];
  *(float4*)(out + (size_t)t * C_DIM + cc) = o0;
  *(float4*)(out + (size_t)t * C_DIM + cc + 4) = o1;
}

extern "C" void kernel_launch(void* const* d_in, const int* in_sizes, int n_in,
                              void* d_out, int out_size, void* d_ws, size_t ws_size,
                              hipStream_t stream) {
  (void)in_sizes; (void)n_in; (void)out_size;
  if (!d_ws || ws_size < WS_NEED) return;  // need ~481 MiB scratch

  const float* x  = (const float*)d_in[0];
  const float* rw = (const float*)d_in[1];
  const float* w1 = (const float*)d_in[2];
  const float* b1 = (const float*)d_in[3];
  const float* w2 = (const float*)d_in[4];
  const float* b2 = (const float*)d_in[5];
  float* out = (float*)d_out;

  char* ws = (char*)d_ws;
  int*       meta  = (int*)(ws + META_OFF);
  _Float16*  xb    = (_Float16*)(ws + XB_OFF);
  _Float16*  w1t   = (_Float16*)(ws + W1T_OFF);
  _Float16*  w2t   = (_Float16*)(ws + W2T_OFF);
  _Float16*  hbuf  = (_Float16*)(ws + HB_OFF);
  _Float16*  ybuf  = (_Float16*)(ws + YB_OFF);
  int*       tok   = (int*)(ws + TOK_OFF);
  float*     gate  = (float*)(ws + GATE_OFF);
  int*       tslot = (int*)(ws + TSLOT_OFF);

  hipMemsetAsync(meta, 0, 256, stream);

  cast_x_kernel<<<(T_TOK * C_DIM / 8) / 256, 256, 0, stream>>>(x, xb);
  transpose_cast_kernel<<<dim3(F_DIM / 32, C_DIM / 32, E_NUM), 256, 0, stream>>>(w1, w1t, C_DIM, F_DIM);
  transpose_cast_kernel<<<dim3(C_DIM / 32, F_DIM / 32, E_NUM), 256, 0, stream>>>(w2, w2t, F_DIM, C_DIM);
  router_kernel<<<T_TOK / 4, 256, 0, stream>>>(x, rw, meta, tok, gate, tslot);
  plan_kernel<<<1, 64, 0, stream>>>(meta);

  // max M-tiles = T*K/256 + E = 136
  gemm1_kernel<<<136 * 16, 512, 0, stream>>>(xb, w1t, b1, hbuf, tok, meta);
  gemm2_kernel<<<136 * 4, 512, 0, stream>>>(hbuf, w2t, b2, ybuf, gate, meta);
  combine_kernel<<<(T_TOK * (C_DIM / 8)) / 256, 256, 0, stream>>>(ybuf, tslot, meta, out);
}

// Round 3
// 1455.388 us; speedup vs baseline: 1.1978x; 1.1183x over previous
//
#include <hip/hip_runtime.h>
#include <hip/hip_fp16.h>

#define T_TOK 16384
#define C_DIM 1024
#define F_DIM 4096
#define E_NUM 8

typedef _Float16 half8 __attribute__((ext_vector_type(8)));
typedef float f32x4 __attribute__((ext_vector_type(4)));

// ---- workspace layout (bytes) ----
static constexpr size_t META_OFF  = 0;
static constexpr size_t XB_OFF    = 256;                                      // x fp16 [T][C]
static constexpr size_t W1T_OFF   = XB_OFF  + (size_t)2*T_TOK*C_DIM;          // w1^T fp16 [E][F][C]
static constexpr size_t W2T_OFF   = W1T_OFF + (size_t)2*E_NUM*C_DIM*F_DIM;    // w2^T fp16 [E][C][F]
static constexpr size_t HB_OFF    = W2T_OFF + (size_t)2*E_NUM*C_DIM*F_DIM;    // h fp16 [T*K][F]
static constexpr size_t YB_OFF    = HB_OFF  + (size_t)2*T_TOK*2*F_DIM;        // y fp16 [T*K][C]
static constexpr size_t TOK_OFF   = YB_OFF  + (size_t)2*T_TOK*2*C_DIM;        // int [E][T]
static constexpr size_t GATE_OFF  = TOK_OFF + (size_t)4*E_NUM*T_TOK;          // float [E][T]
static constexpr size_t TSLOT_OFF = GATE_OFF+ (size_t)4*E_NUM*T_TOK;          // int [T][2]
static constexpr size_t WS_NEED   = TSLOT_OFF + (size_t)4*T_TOK*2;

__device__ __forceinline__ void async16(void* lds, const void* g) {
  __builtin_amdgcn_global_load_lds((const __attribute__((address_space(1))) unsigned int*)g,
                                   (__attribute__((address_space(3))) unsigned int*)lds,
                                   16, 0, 0);
}

// ---- cast x fp32 -> fp16 ----
__global__ __launch_bounds__(256) void cast_x_kernel(const float* __restrict__ x,
                                                     _Float16* __restrict__ xb) {
  size_t i = ((size_t)blockIdx.x * 256 + threadIdx.x) * 8;
  float4 a = *(const float4*)(x + i);
  float4 b = *(const float4*)(x + i + 4);
  half8 h;
  h[0]=(_Float16)a.x; h[1]=(_Float16)a.y; h[2]=(_Float16)a.z; h[3]=(_Float16)a.w;
  h[4]=(_Float16)b.x; h[5]=(_Float16)b.y; h[6]=(_Float16)b.z; h[7]=(_Float16)b.w;
  *(half8*)(xb + i) = h;
}

// ---- transpose + cast: in fp32 [R][Cc] per expert -> out fp16 [Cc][R] ----
__global__ __launch_bounds__(256) void transpose_cast_kernel(const float* __restrict__ in,
                                                             _Float16* __restrict__ outp,
                                                             int R, int Cc) {
  __shared__ float tile[32][33];
  int e = blockIdx.z;
  const float* ip = in + (size_t)e * R * Cc;
  _Float16* op = outp + (size_t)e * R * Cc;
  int c0 = blockIdx.x * 32, r0 = blockIdx.y * 32;
  int tx = threadIdx.x & 31, ty = threadIdx.x >> 5;
  #pragma unroll
  for (int d = 0; d < 32; d += 8)
    tile[ty + d][tx] = ip[(size_t)(r0 + ty + d) * Cc + c0 + tx];
  __syncthreads();
  #pragma unroll
  for (int d = 0; d < 32; d += 8)
    op[(size_t)(c0 + ty + d) * R + r0 + tx] = (_Float16)tile[tx][ty + d];
}

// ---- router: fp64 logits, softmax, top-2 (tie -> lower index), gates ----
__global__ __launch_bounds__(256) void router_kernel(const float* __restrict__ x,
                                                     const float* __restrict__ rw,
                                                     int* __restrict__ counts,
                                                     int* __restrict__ tok,
                                                     float* __restrict__ gate,
                                                     int* __restrict__ tslot) {
  int wv = threadIdx.x >> 6, l = threadIdx.x & 63;
  int t = blockIdx.x * 4 + wv;
  const float* xr = x + (size_t)t * C_DIM;
  double acc[E_NUM] = {};
  #pragma unroll
  for (int j = 0; j < 4; ++j) {
    float4 xv = *(const float4*)(xr + j * 256 + l * 4);
    #pragma unroll
    for (int e = 0; e < E_NUM; ++e) {
      float4 w4 = *(const float4*)(rw + (size_t)e * C_DIM + j * 256 + l * 4);
      acc[e] += (double)xv.x * w4.x + (double)xv.y * w4.y +
                (double)xv.z * w4.z + (double)xv.w * w4.w;
    }
  }
  #pragma unroll
  for (int e = 0; e < E_NUM; ++e)
    #pragma unroll
    for (int off = 32; off; off >>= 1)
      acc[e] += __shfl_xor(acc[e], off, 64);

  if (l == 0) {
    double m = acc[0];
    #pragma unroll
    for (int e = 1; e < E_NUM; ++e) m = acc[e] > m ? acc[e] : m;
    double p[E_NUM], s = 0.0;
    #pragma unroll
    for (int e = 0; e < E_NUM; ++e) { p[e] = exp(acc[e] - m); s += p[e]; }
    int i0 = 0; double b0 = p[0];
    #pragma unroll
    for (int e = 1; e < E_NUM; ++e) if (p[e] > b0) { b0 = p[e]; i0 = e; }
    int i1 = -1; double b1v = -1.0;
    #pragma unroll
    for (int e = 0; e < E_NUM; ++e) if (e != i0 && p[e] > b1v) { b1v = p[e]; i1 = e; }
    double q0 = b0 / s, q1 = b1v / s;
    double den = q0 + q1 + 1e-9;
    float g0 = (float)(q0 / den), g1 = (float)(q1 / den);
    int idx0 = atomicAdd(&counts[i0], 1);
    tok[i0 * T_TOK + idx0] = t; gate[i0 * T_TOK + idx0] = g0;
    tslot[t * 2] = (i0 << 24) | idx0;
    int idx1 = atomicAdd(&counts[i1], 1);
    tok[i1 * T_TOK + idx1] = t; gate[i1 * T_TOK + idx1] = g1;
    tslot[t * 2 + 1] = (i1 << 24) | idx1;
  }
}

// ---- prefix sums ----
__global__ void plan_kernel(int* meta) {
  if (threadIdx.x == 0 && blockIdx.x == 0) {
    int ro = 0, to = 0;
    meta[8] = 0; meta[17] = 0;
    for (int e = 0; e < E_NUM; ++e) {
      int c = meta[e];
      ro += c; to += (c + 255) >> 8;
      meta[9 + e] = ro; meta[18 + e] = to;
    }
  }
}

// ============================================================================
// 256x256 grouped GEMM, BK=64, 8 waves (2Mx4N), 8-phase schedule (T3+T4+T2+T5).
// LDS per buf (64KB): A[ks][256 rows][4 chunks*16B] (32KB) then B same (32KB).
// k-split staging units (per-wave FIFO order): u0,u1=A-ks0; u2,u3=B-ks0;
// u4,u5=A-ks1; u6,u7=B-ks1.  Phase p of tile t stages 2 units of tile t+1.
// Waits: vmcnt(2) @ph1 (gates this tile's ks1 reads at ph2/ph3);
//        vmcnt(4) @ph4 (gates next tile's ks0 reads at ph1). Never drained.
// Swizzle: LDS slot (row, c4s) holds G-chunk c4s ^ ((row>>1)&3)  (involution;
// applied on staging source AND ds_read address; residual 2-way = free).
// ============================================================================

#define GEMM_PHASES(AB_READS_DECL)                                            \
  /* placeholder - phases written inline below */

// ---- grouped GEMM1: h = gelu(x[tok] @ w1[e] + b1[e]) ----
__global__ __launch_bounds__(512, 2) void gemm1_kernel(const _Float16* __restrict__ xb,
                                                       const _Float16* __restrict__ w1t,
                                                       const float* __restrict__ b1,
                                                       _Float16* __restrict__ hbuf,
                                                       const int* __restrict__ tok,
                                                       const int* __restrict__ meta) {
  __shared__ _Float16 smem[65536];   // 2 bufs x (A 32KB + B 32KB)
  __shared__ int tokLds[256];

  int bid = blockIdx.x;
  int swz = (bid & 7) * 272 + (bid >> 3);     // bijective XCD swizzle (nwg=2176)
  int mt = swz >> 4, nt = swz & 15;           // 16 N-tiles (F/256)
  if (mt >= meta[17 + E_NUM]) return;
  int e = 0;
  while (mt >= meta[18 + e]) ++e;
  int ne = meta[e];
  int r0 = (mt - meta[17 + e]) << 8;
  int valid = ne - r0; if (valid > 256) valid = 256;

  int tid = threadIdx.x;
  if (tid < 256) {
    int r = tid < valid ? tid : valid - 1;
    tokLds[tid] = tok[e * T_TOK + r0 + r];
  }
  __syncthreads();

  // staging sources (k-split rounds): thread -> (row = tid>>2, c4slot = tid&3)
  int r_lo = tid >> 2, r_hi = r_lo + 128;
  int chunk = (tid & 3) ^ ((r_lo >> 1) & 3);   // same value for r_hi (128>>1 ≡ 0 mod 4)
  const _Float16* aLo = xb + (size_t)tokLds[r_lo] * C_DIM + chunk * 8;
  const _Float16* aHi = xb + (size_t)tokLds[r_hi] * C_DIM + chunk * 8;
  const _Float16* bLo = w1t + ((size_t)e * F_DIM + nt * 256 + r_lo) * C_DIM + chunk * 8;
  const _Float16* bHi = w1t + ((size_t)e * F_DIM + nt * 256 + r_hi) * C_DIM + chunk * 8;

  char* SM = (char*)smem;
  char* dst = SM + (size_t)tid * 16;   // per-lane linear dest (wave-uniform base + lane*16)

  constexpr int NT = C_DIM / 64;   // 16
  // prologue: tile0 units u0..u7 into buf0
  async16(dst,         aLo);  async16(dst + 8192,  aHi);     // A-ks0
  async16(dst + 32768, bLo);  async16(dst + 40960, bHi);     // B-ks0
  async16(dst + 16384, aLo + 32); async16(dst + 24576, aHi + 32);  // A-ks1
  async16(dst + 49152, bLo + 32); async16(dst + 57344, bHi + 32);  // B-ks1
  asm volatile("s_waitcnt vmcnt(4)" ::: "memory");
  __builtin_amdgcn_s_barrier();

  // per-lane read constants
  int w = tid >> 6, l = tid & 63;
  int wm = w >> 2, wn = w & 3;
  int rl = l & 15, q = l >> 4;
  int swq = ((q ^ ((rl >> 1) & 3)) * 16);
  int aByte = wm * 8192 + rl * 64 + swq;      // + m*1024 + ks*16384
  int bByte = 32768 + wn * 4096 + rl * 64 + swq;  // + n*1024 + ks*16384

  f32x4 acc[8][4] = {};
  int cur = 0;
  for (int t = 0; t < NT; ++t) {
    const char* Tb = SM + cur * 65536;
    char* Sb = SM + (cur ^ 1) * 65536 + (size_t)tid * 16;
    int koff = (t + 1 < NT ? t + 1 : NT - 1) * 64;

    half8 a0[8], a1[8], b0[4], b1f[4];
    // ---- phase 1: read ks0 (12), stage A-ks0(t+1), MFMA (ks0, m0-3) ----
    #pragma unroll
    for (int m = 0; m < 8; ++m) a0[m] = *(const half8*)(Tb + aByte + m * 1024);
    #pragma unroll
    for (int n = 0; n < 4; ++n) b0[n] = *(const half8*)(Tb + bByte + n * 1024);
    async16(Sb, aLo + koff); async16(Sb + 8192, aHi + koff);
    asm volatile("s_waitcnt vmcnt(2)" ::: "memory");
    __builtin_amdgcn_s_barrier();
    __builtin_amdgcn_s_setprio(1);
    #pragma unroll
    for (int m = 0; m < 4; ++m)
      #pragma unroll
      for (int n = 0; n < 4; ++n)
        acc[m][n] = __builtin_amdgcn_mfma_f32_16x16x32_f16(a0[m], b0[n], acc[m][n], 0, 0, 0);
    __builtin_amdgcn_s_setprio(0);
    __builtin_amdgcn_s_barrier();

    // ---- phase 2: read A-ks1 (8), stage B-ks0(t+1), MFMA (ks0, m4-7) ----
    #pragma unroll
    for (int m = 0; m < 8; ++m) a1[m] = *(const half8*)(Tb + 16384 + aByte + m * 1024);
    async16(Sb + 32768, bLo + koff); async16(Sb + 40960, bHi + koff);
    __builtin_amdgcn_s_barrier();
    __builtin_amdgcn_s_setprio(1);
    #pragma unroll
    for (int m = 0; m < 4; ++m)
      #pragma unroll
      for (int n = 0; n < 4; ++n)
        acc[4 + m][n] = __builtin_amdgcn_mfma_f32_16x16x32_f16(a0[4 + m], b0[n], acc[4 + m][n], 0, 0, 0);
    __builtin_amdgcn_s_setprio(0);
    __builtin_amdgcn_s_barrier();

    // ---- phase 3: read B-ks1 (4), stage A-ks1(t+1), MFMA (ks1, m0-3) ----
    #pragma unroll
    for (int n = 0; n < 4; ++n) b1f[n] = *(const half8*)(Tb + 16384 + bByte + n * 1024);
    async16(Sb + 16384, aLo + koff + 32); async16(Sb + 24576, aHi + koff + 32);
    __builtin_amdgcn_s_barrier();
    __builtin_amdgcn_s_setprio(1);
    #pragma unroll
    for (int m = 0; m < 4; ++m)
      #pragma unroll
      for (int n = 0; n < 4; ++n)
        acc[m][n] = __builtin_amdgcn_mfma_f32_16x16x32_f16(a1[m], b1f[n], acc[m][n], 0, 0, 0);
    __builtin_amdgcn_s_setprio(0);
    __builtin_amdgcn_s_barrier();

    // ---- phase 4: stage B-ks1(t+1), vmcnt(4), MFMA (ks1, m4-7) ----
    async16(Sb + 49152, bLo + koff + 32); async16(Sb + 57344, bHi + koff + 32);
    asm volatile("s_waitcnt vmcnt(4)" ::: "memory");
    __builtin_amdgcn_s_barrier();
    __builtin_amdgcn_s_setprio(1);
    #pragma unroll
    for (int m = 0; m < 4; ++m)
      #pragma unroll
      for (int n = 0; n < 4; ++n)
        acc[4 + m][n] = __builtin_amdgcn_mfma_f32_16x16x32_f16(a1[4 + m], b1f[n], acc[4 + m][n], 0, 0, 0);
    __builtin_amdgcn_s_setprio(0);
    __builtin_amdgcn_s_barrier();

    cur ^= 1;
  }

  // epilogue
  int hbase = meta[8 + e] + r0;
  float bv[4];
  #pragma unroll
  for (int n = 0; n < 4; ++n)
    bv[n] = b1[(size_t)e * F_DIM + nt * 256 + wn * 64 + n * 16 + (l & 15)];
  #pragma unroll
  for (int m = 0; m < 8; ++m) {
    int rb = wm * 128 + m * 16 + (l >> 4) * 4;
    #pragma unroll
    for (int n = 0; n < 4; ++n) {
      int col = nt * 256 + wn * 64 + n * 16 + (l & 15);
      #pragma unroll
      for (int r = 0; r < 4; ++r) {
        int row = rb + r;
        if (row < valid) {
          float pre = acc[m][n][r] + bv[n];
          float g = 0.5f * pre * (1.0f + erff(pre * 0.70710678118654752f));
          hbuf[(size_t)(hbase + row) * F_DIM + col] = (_Float16)g;
        }
      }
    }
  }
}

// ---- grouped GEMM2: ybuf = gate * (h @ w2[e] + b2[e]) ----
__global__ __launch_bounds__(512, 2) void gemm2_kernel(const _Float16* __restrict__ hbuf,
                                                       const _Float16* __restrict__ w2t,
                                                       const float* __restrict__ b2,
                                                       _Float16* __restrict__ ybuf,
                                                       const float* __restrict__ gate,
                                                       const int* __restrict__ meta) {
  __shared__ _Float16 smem[65536];
  __shared__ float gateLds[256];

  int bid = blockIdx.x;
  int swz = (bid & 7) * 68 + (bid >> 3);      // bijective XCD swizzle (nwg=544)
  int mt = swz >> 2, nt = swz & 3;            // 4 N-tiles (C/256)
  if (mt >= meta[17 + E_NUM]) return;
  int e = 0;
  while (mt >= meta[18 + e]) ++e;
  int ne = meta[e];
  int r0 = (mt - meta[17 + e]) << 8;
  int valid = ne - r0; if (valid > 256) valid = 256;
  int hbase = meta[8 + e] + r0;

  int tid = threadIdx.x;
  if (tid < 256) {
    int r = tid < valid ? tid : valid - 1;
    gateLds[tid] = gate[e * T_TOK + r0 + r];
  }
  __syncthreads();

  int r_lo = tid >> 2, r_hi = r_lo + 128;
  int chunk = (tid & 3) ^ ((r_lo >> 1) & 3);
  int rc_lo = r_lo < valid ? r_lo : valid - 1;
  int rc_hi = r_hi < valid ? r_hi : valid - 1;
  const _Float16* aLo = hbuf + (size_t)(hbase + rc_lo) * F_DIM + chunk * 8;
  const _Float16* aHi = hbuf + (size_t)(hbase + rc_hi) * F_DIM + chunk * 8;
  const _Float16* bLo = w2t + ((size_t)e * C_DIM + nt * 256 + r_lo) * F_DIM + chunk * 8;
  const _Float16* bHi = w2t + ((size_t)e * C_DIM + nt * 256 + r_hi) * F_DIM + chunk * 8;

  char* SM = (char*)smem;
  char* dst = SM + (size_t)tid * 16;

  constexpr int NT = F_DIM / 64;   // 64
  async16(dst,         aLo);  async16(dst + 8192,  aHi);
  async16(dst + 32768, bLo);  async16(dst + 40960, bHi);
  async16(dst + 16384, aLo + 32); async16(dst + 24576, aHi + 32);
  async16(dst + 49152, bLo + 32); async16(dst + 57344, bHi + 32);
  asm volatile("s_waitcnt vmcnt(4)" ::: "memory");
  __builtin_amdgcn_s_barrier();

  int w = tid >> 6, l = tid & 63;
  int wm = w >> 2, wn = w & 3;
  int rl = l & 15, q = l >> 4;
  int swq = ((q ^ ((rl >> 1) & 3)) * 16);
  int aByte = wm * 8192 + rl * 64 + swq;
  int bByte = 32768 + wn * 4096 + rl * 64 + swq;

  f32x4 acc[8][4] = {};
  int cur = 0;
  for (int t = 0; t < NT; ++t) {
    const char* Tb = SM + cur * 65536;
    char* Sb = SM + (cur ^ 1) * 65536 + (size_t)tid * 16;
    int koff = (t + 1 < NT ? t + 1 : NT - 1) * 64;

    half8 a0[8], a1[8], b0[4], b1f[4];
    #pragma unroll
    for (int m = 0; m < 8; ++m) a0[m] = *(const half8*)(Tb + aByte + m * 1024);
    #pragma unroll
    for (int n = 0; n < 4; ++n) b0[n] = *(const half8*)(Tb + bByte + n * 1024);
    async16(Sb, aLo + koff); async16(Sb + 8192, aHi + koff);
    asm volatile("s_waitcnt vmcnt(2)" ::: "memory");
    __builtin_amdgcn_s_barrier();
    __builtin_amdgcn_s_setprio(1);
    #pragma unroll
    for (int m = 0; m < 4; ++m)
      #pragma unroll
      for (int n = 0; n < 4; ++n)
        acc[m][n] = __builtin_amdgcn_mfma_f32_16x16x32_f16(a0[m], b0[n], acc[m][n], 0, 0, 0);
    __builtin_amdgcn_s_setprio(0);
    __builtin_amdgcn_s_barrier();

    #pragma unroll
    for (int m = 0; m < 8; ++m) a1[m] = *(const half8*)(Tb + 16384 + aByte + m * 1024);
    async16(Sb + 32768, bLo + koff); async16(Sb + 40960, bHi + koff);
    __builtin_amdgcn_s_barrier();
    __builtin_amdgcn_s_setprio(1);
    #pragma unroll
    for (int m = 0; m < 4; ++m)
      #pragma unroll
      for (int n = 0; n < 4; ++n)
        acc[4 + m][n] = __builtin_amdgcn_mfma_f32_16x16x32_f16(a0[4 + m], b0[n], acc[4 + m][n], 0, 0, 0);
    __builtin_amdgcn_s_setprio(0);
    __builtin_amdgcn_s_barrier();

    #pragma unroll
    for (int n = 0; n < 4; ++n) b1f[n] = *(const half8*)(Tb + 16384 + bByte + n * 1024);
    async16(Sb + 16384, aLo + koff + 32); async16(Sb + 24576, aHi + koff + 32);
    __builtin_amdgcn_s_barrier();
    __builtin_amdgcn_s_setprio(1);
    #pragma unroll
    for (int m = 0; m < 4; ++m)
      #pragma unroll
      for (int n = 0; n < 4; ++n)
        acc[m][n] = __builtin_amdgcn_mfma_f32_16x16x32_f16(a1[m], b1f[n], acc[m][n], 0, 0, 0);
    __builtin_amdgcn_s_setprio(0);
    __builtin_amdgcn_s_barrier();

    async16(Sb + 49152, bLo + koff + 32); async16(Sb + 57344, bHi + koff + 32);
    asm volatile("s_waitcnt vmcnt(4)" ::: "memory");
    __builtin_amdgcn_s_barrier();
    __builtin_amdgcn_s_setprio(1);
    #pragma unroll
    for (int m = 0; m < 4; ++m)
      #pragma unroll
      for (int n = 0; n < 4; ++n)
        acc[4 + m][n] = __builtin_amdgcn_mfma_f32_16x16x32_f16(a1[4 + m], b1f[n], acc[4 + m][n], 0, 0, 0);
    __builtin_amdgcn_s_setprio(0);
    __builtin_amdgcn_s_barrier();

    cur ^= 1;
  }

  float bv[4];
  #pragma unroll
  for (int n = 0; n < 4; ++n)
    bv[n] = b2[(size_t)e * C_DIM + nt * 256 + wn * 64 + n * 16 + (l & 15)];
  #pragma unroll
  for (int m = 0; m < 8; ++m) {
    int rb = wm * 128 + m * 16 + (l >> 4) * 4;
    #pragma unroll
    for (int n = 0; n < 4; ++n) {
      int col = nt * 256 + wn * 64 + n * 16 + (l & 15);
      #pragma unroll
      for (int r = 0; r < 4; ++r) {
        int row = rb + r;
        if (row < valid) {
          float val = gateLds[row] * (acc[m][n][r] + bv[n]);
          ybuf[(size_t)(hbase + row) * C_DIM + col] = (_Float16)val;
        }
      }
    }
  }
}

// ---- combine: out[t] = y(slot0) + y(slot1) ----
__global__ __launch_bounds__(256) void combine_kernel(const _Float16* __restrict__ ybuf,
                                                      const int* __restrict__ tslot,
                                                      const int* __restrict__ meta,
                                                      float* __restrict__ out) {
  int gid = blockIdx.x * 256 + threadIdx.x;
  int t = gid >> 7;
  int cc = (gid & 127) << 3;
  int s0 = tslot[t * 2], s1 = tslot[t * 2 + 1];
  size_t r0 = (size_t)meta[8 + (s0 >> 24)] + (s0 & 0xFFFFFF);
  size_t r1 = (size_t)meta[8 + (s1 >> 24)] + (s1 & 0xFFFFFF);
  half8 y0 = *(const half8*)(ybuf + r0 * C_DIM + cc);
  half8 y1 = *(const half8*)(ybuf + r1 * C_DIM + cc);
  float4 o0, o1;
  o0.x = (float)y0[0] + (float)y1[0];
  o0.y = (float)y0[1] + (float)y1[1];
  o0.z = (float)y0[2] + (float)y1[2];
  o0.w = (float)y0[3] + (float)y1[3];
  o1.x = (float)y0[4] + (float)y1[4];
  o1.y = (float)y0[5] + (float)y1[5];
  o1.z = (float)y0[6] + (float)y1[6];
  o1.w = (float)y0[7] + (float)y1[7];
  *(float4*)(out + (size_t)t * C_DIM + cc) = o0;
  *(float4*)(out + (size_t)t * C_DIM + cc + 4) = o1;
}

extern "C" void kernel_launch(void* const* d_in, const int* in_sizes, int n_in,
                              void* d_out, int out_size, void* d_ws, size_t ws_size,
                              hipStream_t stream) {
  (void)in_sizes; (void)n_in; (void)out_size;
  if (!d_ws || ws_size < WS_NEED) return;  // need ~481 MiB scratch

  const float* x  = (const float*)d_in[0];
  const float* rw = (const float*)d_in[1];
  const float* w1 = (const float*)d_in[2];
  const float* b1 = (const float*)d_in[3];
  const float* w2 = (const float*)d_in[4];
  const float* b2 = (const float*)d_in[5];
  float* out = (float*)d_out;

  char* ws = (char*)d_ws;
  int*       meta  = (int*)(ws + META_OFF);
  _Float16*  xb    = (_Float16*)(ws + XB_OFF);
  _Float16*  w1t   = (_Float16*)(ws + W1T_OFF);
  _Float16*  w2t   = (_Float16*)(ws + W2T_OFF);
  _Float16*  hbuf  = (_Float16*)(ws + HB_OFF);
  _Float16*  ybuf  = (_Float16*)(ws + YB_OFF);
  int*       tok   = (int*)(ws + TOK_OFF);
  float*     gate  = (float*)(ws + GATE_OFF);
  int*       tslot = (int*)(ws + TSLOT_OFF);

  hipMemsetAsync(meta, 0, 256, stream);

  cast_x_kernel<<<(T_TOK * C_DIM / 8) / 256, 256, 0, stream>>>(x, xb);
  transpose_cast_kernel<<<dim3(F_DIM / 32, C_DIM / 32, E_NUM), 256, 0, stream>>>(w1, w1t, C_DIM, F_DIM);
  transpose_cast_kernel<<<dim3(C_DIM / 32, F_DIM / 32, E_NUM), 256, 0, stream>>>(w2, w2t, F_DIM, C_DIM);
  router_kernel<<<T_TOK / 4, 256, 0, stream>>>(x, rw, meta, tok, gate, tslot);
  plan_kernel<<<1, 64, 0, stream>>>(meta);

  // max M-tiles = T*K/256 + E = 136
  gemm1_kernel<<<136 * 16, 512, 0, stream>>>(xb, w1t, b1, hbuf, tok, meta);
  gemm2_kernel<<<136 * 4, 512, 0, stream>>>(hbuf, w2t, b2, ybuf, gate, meta);
  combine_kernel<<<(T_TOK * (C_DIM / 8)) / 256, 256, 0, stream>>>(ybuf, tslot, meta, out);
}